// Round 7
// baseline (248.911 us; speedup 1.0000x reference)
//
#include <hip/hip_runtime.h>

// B=8, C=512, H=W=32, HW=1024, M=8192. scale = 1/sqrt(512).
// prep (x transpose->bf16, W pack->bf16)
// gemm_qkz (bf16 MFMA, R5-hybrid: A per-lane global, B staged LDS frag-ordered,
//           8 barriers; q|k -> fp8 qk8 via v_cvt_pk_fp8_f32 (+bias), z -> bf16)
// gemm_scores (R7: MX-fp8 MFMA 32x32x64 (R6-verified lane maps) + R5's
//              8-wave occupancy. Block 512 = 4 row-groups x 2 col-halves;
//              wave (wr,wc) owns rows wr*32..+32, cols wc*64..+64 of each
//              staged 128-col tile. Halved LDS traffic (R6 win) at 2x R6's
//              waves (R5 win). Partial per-row max -> wsmx[16][8192], folded
//              in softmax_xw.)
// softmax_xw ; epilogue_out (out = z*xw + b6, LDS transpose)

typedef __attribute__((ext_vector_type(8))) short bf16x8;
typedef __attribute__((ext_vector_type(4))) float f32x4;
typedef __attribute__((ext_vector_type(16))) float f32x16;
typedef __attribute__((ext_vector_type(2))) long long i64x2;
typedef __attribute__((ext_vector_type(8))) int i32x8;

__device__ __forceinline__ unsigned short f2bf(float f) {
  unsigned u = __builtin_bit_cast(unsigned, f);
  u += 0x7FFFu + ((u >> 16) & 1u);
  return (unsigned short)(u >> 16);
}

__device__ __forceinline__ float bf2f(unsigned short b) {
  return __builtin_bit_cast(float, (unsigned)b << 16);
}

__device__ __forceinline__ void gload_lds16(const void* g, void* l) {
  __builtin_amdgcn_global_load_lds(
      (const __attribute__((address_space(1))) unsigned int*)g,
      (__attribute__((address_space(3))) unsigned int*)l, 16, 0, 0);
}

// ---------------------------------------------------------------------------
// prep: blocks [0,1024): transpose x [b][c][p] -> xt [b*1024+p][c] bf16
//       blocks [1024,1792): pack Wq|Wk|W6 -> wcat bf16 [1536][512]
__global__ __launch_bounds__(256) void prep(const float* __restrict__ x,
                                            const float* __restrict__ Wq,
                                            const float* __restrict__ Wk,
                                            const float* __restrict__ W6,
                                            short* __restrict__ xt,
                                            short* __restrict__ wcat) {
  const int bid = blockIdx.x, u = threadIdx.x;
  if (bid < 1024) {
    const int p0 = (bid & 15) * 64, c0 = ((bid >> 4) & 7) * 64, b = bid >> 7;
    __shared__ float t[64][65];
    {
      const int p4 = u & 15, cr = u >> 4;
      for (int cc = 0; cc < 4; ++cc) {
        const int c = cc * 16 + cr;
        const float4 v = *(const float4*)&x[((size_t)(b * 512 + c0 + c)) * 1024 + p0 + p4 * 4];
        t[p4 * 4 + 0][c] = v.x; t[p4 * 4 + 1][c] = v.y;
        t[p4 * 4 + 2][c] = v.z; t[p4 * 4 + 3][c] = v.w;
      }
    }
    __syncthreads();
    {
      const int c4 = u & 15, pr = u >> 4;
      for (int pp = 0; pp < 4; ++pp) {
        const int p = pp * 16 + pr;
        ushort4 o;
        o.x = f2bf(t[p][c4 * 4 + 0]); o.y = f2bf(t[p][c4 * 4 + 1]);
        o.z = f2bf(t[p][c4 * 4 + 2]); o.w = f2bf(t[p][c4 * 4 + 3]);
        *(ushort4*)&xt[((size_t)(b * 1024 + p0 + p)) * 512 + c0 + c4 * 4] = o;
      }
    }
  } else {
    const int i = (bid - 1024) * 256 + u;
    const int idx = i * 4;
    const float* src = (idx < 262144) ? Wq : (idx < 524288) ? Wk : W6;
    const float4 v = *(const float4*)&src[idx & 262143];
    ushort4 o;
    o.x = f2bf(v.x); o.y = f2bf(v.y); o.z = f2bf(v.z); o.w = f2bf(v.w);
    *(ushort4*)&wcat[idx] = o;
  }
}

// ---------------------------------------------------------------------------
// gemm_qkz: C[8192][1536] = xt @ wcat^T, R5-hybrid structure.
// Block 128x128, grid (64,12); wave w owns rows [m0+w*32,+32): acc[2][8].
// A streamed per-lane from global; B staged in LDS in 4 K-chunks, 32 KB LDS.
// Cols 0..1023 -> qk8 fp8 (+bias, HW v_cvt_pk_fp8_f32); 1024..1535 -> z bf16.
__global__ __launch_bounds__(256) void gemm_qkz(const short* __restrict__ xt,
                                                const short* __restrict__ wcat,
                                                const float* __restrict__ bq,
                                                const float* __restrict__ bk,
                                                unsigned char* __restrict__ qk8,
                                                short* __restrict__ z) {
  __shared__ short lds_b[16384];  // 32 KB: 8 j-groups x 4 kb x 512 shorts
  const int tid = threadIdx.x, w = tid >> 6, lane = tid & 63;
  const int quad = lane >> 4, lcol = lane & 15;
  const int srow = lane & 15, skq = lane >> 4;  // staging: row in j-group, 8-elem quad
  const int m0 = blockIdx.x * 128, n0 = blockIdx.y * 128;

  f32x4 acc[2][8];
#pragma unroll
  for (int rg = 0; rg < 2; ++rg)
#pragma unroll
    for (int j = 0; j < 8; ++j)
#pragma unroll
      for (int r = 0; r < 4; ++r) acc[rg][j][r] = 0.f;

  // A: per-lane; row = m0 + w*32 + rg*16 + srow, k-elems kh*128 + kb*32 + skq*8
  const short* Abase = xt + (size_t)(m0 + w * 32 + srow) * 512 + skq * 8;
  // B: staging source; row = n0 + j*16 + srow
  const short* Bbase = wcat + (size_t)(n0 + srow) * 512 + skq * 8;

#pragma unroll
  for (int kh = 0; kh < 4; ++kh) {
    const int ke = kh * 128;  // k-elem base of this chunk
    __syncthreads();  // previous chunk fully consumed before overwrite
#pragma unroll
    for (int jj = 0; jj < 2; ++jj) {
      const int j = w * 2 + jj;
#pragma unroll
      for (int kb = 0; kb < 4; ++kb)
        gload_lds16(Bbase + (size_t)(j * 16) * 512 + ke + kb * 32,
                    lds_b + j * 2048 + kb * 512);
    }
    // prefetch this chunk's A (2 rg x 4 kb x 16 B) while glds are in flight
    bf16x8 af[2][4];
#pragma unroll
    for (int rg = 0; rg < 2; ++rg)
#pragma unroll
      for (int kb = 0; kb < 4; ++kb)
        af[rg][kb] = *(const bf16x8*)(Abase + (size_t)rg * 16 * 512 + ke + kb * 32);
    __syncthreads();  // B chunk ready
#pragma unroll
    for (int kb = 0; kb < 4; ++kb) {
#pragma unroll
      for (int j = 0; j < 8; ++j) {
        const bf16x8 bf = *(const bf16x8*)&lds_b[j * 2048 + kb * 512 + lane * 8];
#pragma unroll
        for (int rg = 0; rg < 2; ++rg)
          acc[rg][j] = __builtin_amdgcn_mfma_f32_16x16x32_bf16(af[rg][kb], bf, acc[rg][j], 0, 0, 0);
      }
    }
  }

  const int region = (int)blockIdx.y >> 2;  // 0=q, 1=k, 2=z (uniform per block)
  if (region < 2) {
    const float* bias = region ? bk : bq;
#pragma unroll
    for (int rg = 0; rg < 2; ++rg) {
      const int row = m0 + w * 32 + rg * 16 + quad * 4;
#pragma unroll
      for (int j = 0; j < 8; ++j) {
        const int col = n0 + j * 16 + lcol;
        const float bv = bias[col & 511];
        const int p01 = __builtin_amdgcn_cvt_pk_fp8_f32(
            acc[rg][j][0] + bv, acc[rg][j][1] + bv, 0, false);
        const int p23 = __builtin_amdgcn_cvt_pk_fp8_f32(
            acc[rg][j][2] + bv, acc[rg][j][3] + bv, 0, false);
        qk8[(size_t)(row + 0) * 1024 + col] = (unsigned char)(p01 & 0xFF);
        qk8[(size_t)(row + 1) * 1024 + col] = (unsigned char)((p01 >> 8) & 0xFF);
        qk8[(size_t)(row + 2) * 1024 + col] = (unsigned char)(p23 & 0xFF);
        qk8[(size_t)(row + 3) * 1024 + col] = (unsigned char)((p23 >> 8) & 0xFF);
      }
    }
  } else {
#pragma unroll
    for (int rg = 0; rg < 2; ++rg) {
      const int row = m0 + w * 32 + rg * 16 + quad * 4;
#pragma unroll
      for (int j = 0; j < 8; ++j) {
        const int col = n0 - 1024 + j * 16 + lcol;
#pragma unroll
        for (int r = 0; r < 4; ++r)
          z[(size_t)(row + r) * 512 + col] = (short)f2bf(acc[rg][j][r]);
      }
    }
  }
}

// ---------------------------------------------------------------------------
// gemm_scores R7: q @ k^T via MX-fp8 mfma_scale_f32_32x32x64_f8f6f4, unit
// scales (lane maps hardware-verified by R6's passing run).
// grid (64 row-tiles, 8 images), block 512 = 8 waves: wave w = (wr = w>>1,
// wc = w&1) owns rows [m0+wr*32,+32) x cols [wc*64,+64) of each staged
// 128-col subtile. ns-loop over the image's 8 col-subtiles; per ns the
// verified single-buffer discipline:
//   sync ; stage 64 KB (wave stages j-group wr, k-half wc: 8 gload_lds) ;
//   sync ; compute 16 MFMA (8 kc x 2 jj) ; fold vmax.
// LDS [4 j][8 kc][2 p][1 KB]; B frag = two b128 at lane*16 / +1024,
// conflict-free. A rolling per-kc from global (ns-invariant -> L1-hot).
// Per-row max is split across the 2 wc waves -> wsmx[img*2+wc][row]
// ([16][8192]); softmax_xw folds the pair. C/D row map (R6-verified):
// row_local = (r&3) + 8*(r>>2) + 4*(lane>>5).
__global__ __launch_bounds__(512) void gemm_scores(const unsigned char* __restrict__ qk8,
                                                   float* __restrict__ wsmx) {
  __shared__ unsigned char lds_b[65536];  // 4 j x 8 kc x 2 p x 1 KB
  const int tid = threadIdx.x, w = tid >> 6, lane = tid & 63;
  const int l31 = lane & 31, lh = lane >> 5;
  const int wr = w >> 1, wc = w & 1;
  const int m0 = blockIdx.x * 128;
  const int img = blockIdx.y;  // image = 1024-col stripe
  const int n0 = img * 1024;

  // A source (q half): row = m0 + wr*32 + l31, k-bytes = kc*64 + lh*32 + [0,32)
  const unsigned char* Abase = qk8 + (size_t)(m0 + wr * 32 + l31) * 1024 + lh * 32;
  // B staging source (k half): wave stages j-group wr, k-half wc.
  // col-row = n0 + ns*128 + wr*32 + l31 ; k-bytes = (wc*4+kc')*64 + lh*32 + p*16
  const unsigned char* Bbase =
      qk8 + (size_t)(n0 + wr * 32 + l31) * 1024 + 512 + wc * 256 + lh * 32;
  unsigned char* ldsst = lds_b + wr * 16384 + wc * 8192;

  f32x16 acc[2];
  float vmax[16];
#pragma unroll
  for (int r = 0; r < 16; ++r) vmax[r] = -1e30f;

  for (int ns = 0; ns < 8; ++ns) {
    __syncthreads();  // previous ns fully consumed before overwrite
#pragma unroll
    for (int kcp = 0; kcp < 4; ++kcp)
#pragma unroll
      for (int p = 0; p < 2; ++p)
        gload_lds16(Bbase + ns * 131072 + kcp * 64 + p * 16,
                    ldsst + kcp * 2048 + p * 1024);
    __syncthreads();  // all 64 KB staged (single vmcnt-0 drain per ns)

#pragma unroll
    for (int jj = 0; jj < 2; ++jj)
#pragma unroll
      for (int r = 0; r < 16; ++r) acc[jj][r] = 0.f;

#pragma unroll
    for (int kc = 0; kc < 8; ++kc) {
      const i32x8 af = *(const i32x8*)(Abase + kc * 64);
#pragma unroll
      for (int jj = 0; jj < 2; ++jj) {
        const int j = wc * 2 + jj;
        i32x8 bf;
        *(i64x2*)&bf = *(const i64x2*)&lds_b[j * 16384 + kc * 2048 + lane * 16];
        *((i64x2*)&bf + 1) =
            *(const i64x2*)&lds_b[j * 16384 + kc * 2048 + 1024 + lane * 16];
        acc[jj] = __builtin_amdgcn_mfma_scale_f32_32x32x64_f8f6f4(
            af, bf, acc[jj], 0, 0, 0, 0x7F7F7F7F, 0, 0x7F7F7F7F);
      }
    }

    // fold this n-sub's cols into the running per-row max (in-lane part)
#pragma unroll
    for (int jj = 0; jj < 2; ++jj)
#pragma unroll
      for (int r = 0; r < 16; ++r) vmax[r] = fmaxf(vmax[r], acc[jj][r]);
  }

  // cross-lane reduce over 32 cols (xor<32 stays within each lh half) and
  // write this wave's partial per-row max: wsmx[img*2+wc][row]
#pragma unroll
  for (int r = 0; r < 16; ++r) {
    float v = vmax[r];
#pragma unroll
    for (int off = 1; off < 32; off <<= 1) v = fmaxf(v, __shfl_xor(v, off));
    if (l31 == 0) {
      const int row_local = (r & 3) + 8 * (r >> 2) + 4 * lh;
      wsmx[(size_t)(img * 2 + wc) * 8192 + m0 + wr * 32 + row_local] = v;
    }
  }
}

// ---------------------------------------------------------------------------
// softmax_xw: logit[m] = scale * mean_img( per-image max ); softmax per image.
// wsmx is [16][8192]: per (image, col-half) partial maxes from gemm_scores.
__global__ __launch_bounds__(1024) void softmax_xw(const float* __restrict__ wsmx,
                                                   float* __restrict__ xw) {
  const int b = blockIdx.x, p = threadIdx.x;
  const int m = b * 1024 + p;
  float s = 0.f;
#pragma unroll
  for (int img = 0; img < 8; ++img)
    s += fmaxf(wsmx[(size_t)(img * 2 + 0) * 8192 + m],
               wsmx[(size_t)(img * 2 + 1) * 8192 + m]);
  const float logit = s * 0.005524271728019903f;  // (1/8) * (1/sqrt(512))
  __shared__ float red[16];
  float v = logit;
#pragma unroll
  for (int off = 32; off >= 1; off >>= 1) v = fmaxf(v, __shfl_xor(v, off));
  if ((p & 63) == 0) red[p >> 6] = v;
  __syncthreads();
  float bmax = red[0];
#pragma unroll
  for (int t = 1; t < 16; ++t) bmax = fmaxf(bmax, red[t]);
  const float e = expf(logit - bmax);
  float sv = e;
#pragma unroll
  for (int off = 32; off >= 1; off >>= 1) sv += __shfl_xor(sv, off);
  __syncthreads();
  if ((p & 63) == 0) red[p >> 6] = sv;
  __syncthreads();
  float bsum = 0.f;
#pragma unroll
  for (int t = 0; t < 16; ++t) bsum += red[t];
  xw[m] = e / bsum;
}

// ---------------------------------------------------------------------------
// epilogue_out: out[b][co][p] = z[b*1024+p][co] * xw[b*1024+p] + b6[co]
// z in bf16. grid (16 p-tiles, 8 c-tiles, 8 b), block 256.
__global__ __launch_bounds__(256) void epilogue_out(const short* __restrict__ z,
                                                    const float* __restrict__ xw,
                                                    const float* __restrict__ b6,
                                                    float* __restrict__ out) {
  const int p0 = blockIdx.x * 64, c0 = blockIdx.y * 64, b = blockIdx.z;
  __shared__ float t[64][65];  // t[co][p]
  const int u = threadIdx.x;
  {
    const int c4 = u & 15, pr = u >> 4;
    for (int pp = 0; pp < 4; ++pp) {
      const int p = pp * 16 + pr;
      const ushort4 v = *(const ushort4*)&z[((size_t)(b * 1024 + p0 + p)) * 512 + c0 + c4 * 4];
      t[c4 * 4 + 0][p] = bf2f(v.x);
      t[c4 * 4 + 1][p] = bf2f(v.y);
      t[c4 * 4 + 2][p] = bf2f(v.z);
      t[c4 * 4 + 3][p] = bf2f(v.w);
    }
  }
  __syncthreads();
  {
    const int p4 = u & 15, cr = u >> 4;
    const float4 wv = *(const float4*)&xw[b * 1024 + p0 + p4 * 4];
    for (int cc = 0; cc < 4; ++cc) {
      const int co = cc * 16 + cr;
      const float bias = b6[c0 + co];
      float4 o;
      o.x = t[co][p4 * 4 + 0] * wv.x + bias;
      o.y = t[co][p4 * 4 + 1] * wv.y + bias;
      o.z = t[co][p4 * 4 + 2] * wv.z + bias;
      o.w = t[co][p4 * 4 + 3] * wv.w + bias;
      *(float4*)&out[((size_t)(b * 512 + c0 + co)) * 1024 + p0 + p4 * 4] = o;
    }
  }
}

// ---------------------------------------------------------------------------
extern "C" void kernel_launch(void* const* d_in, const int* in_sizes, int n_in,
                              void* d_out, int out_size, void* d_ws, size_t ws_size,
                              hipStream_t stream) {
  const float* x  = (const float*)d_in[0];
  const float* Wq = (const float*)d_in[1];
  const float* bq = (const float*)d_in[2];
  const float* Wk = (const float*)d_in[3];
  const float* bk = (const float*)d_in[4];
  const float* W6 = (const float*)d_in[5];
  const float* b6 = (const float*)d_in[6];
  float* out = (float*)d_out;

  char* ws = (char*)d_ws;
  short* xt          = (short*)(ws + 0);               //  8 MB  bf16 [8192][512]
  short* wcat        = (short*)(ws + 8388608);         //  1.5MB bf16 [1536][512]
  unsigned char* qk8 = (unsigned char*)(ws + 10485760);//  8 MB  fp8  [8192][1024]
  short* z           = (short*)(ws + 18874368);        //  8 MB  bf16 [8192][512]
  float* wsmx        = (float*)(ws + 27262976);        // 512KB fp32 [16][8192]
  float* xw          = (float*)(ws + 29360128);        // 32 KB  fp32 [8192]

  prep<<<1792, 256, 0, stream>>>(x, Wq, Wk, W6, xt, wcat);
  gemm_qkz<<<dim3(64, 12), 256, 0, stream>>>(xt, wcat, bq, bk, qk8, z);
  gemm_scores<<<dim3(64, 8), 512, 0, stream>>>(qk8, wsmx);
  softmax_xw<<<8, 1024, 0, stream>>>(wsmx, xw);
  epilogue_out<<<dim3(16, 8, 8), 256, 0, stream>>>(z, xw, b6, out);
}

// Round 8
// 229.947 us; speedup vs baseline: 1.0825x; 1.0825x over previous
//
#include <hip/hip_runtime.h>

// B=8, C=512, H=W=32, HW=1024, M=8192. scale = 1/sqrt(512).
// prep (x transpose->bf16, W pack->bf16)
// gemm_qkz (bf16 MFMA, R5-hybrid: A per-lane global, B staged LDS frag-ordered,
//           8 barriers; q|k -> fp8 qk8 via v_cvt_pk_fp8_f32 (+bias), z -> bf16)
// gemm_scores (R8: MX-fp8 MFMA 32x32x64. Key insight: "wave owns 32 rows x
//              full image" caps total waves at 2048 = 8/CU (R6 20.9% occ,
//              R7 spilled fighting it). Split image cols across BLOCKS:
//              grid (64,8,2) = 1024 blocks x 4 waves = 4096 waves = 16/CU.
//              Block: 128 rows x 512 cols, ns-loop 8 x 64-col tiles, 32 KB
//              LDS -> 4 blocks/CU. Partial max -> wsmx[16][8192], softmax
//              folds pairs (R7-verified).)
// softmax_xw ; epilogue_out (out = z*xw + b6, LDS transpose)

typedef __attribute__((ext_vector_type(8))) short bf16x8;
typedef __attribute__((ext_vector_type(4))) float f32x4;
typedef __attribute__((ext_vector_type(16))) float f32x16;
typedef __attribute__((ext_vector_type(2))) long long i64x2;
typedef __attribute__((ext_vector_type(8))) int i32x8;

__device__ __forceinline__ unsigned short f2bf(float f) {
  unsigned u = __builtin_bit_cast(unsigned, f);
  u += 0x7FFFu + ((u >> 16) & 1u);
  return (unsigned short)(u >> 16);
}

__device__ __forceinline__ float bf2f(unsigned short b) {
  return __builtin_bit_cast(float, (unsigned)b << 16);
}

__device__ __forceinline__ void gload_lds16(const void* g, void* l) {
  __builtin_amdgcn_global_load_lds(
      (const __attribute__((address_space(1))) unsigned int*)g,
      (__attribute__((address_space(3))) unsigned int*)l, 16, 0, 0);
}

// ---------------------------------------------------------------------------
// prep: blocks [0,1024): transpose x [b][c][p] -> xt [b*1024+p][c] bf16
//       blocks [1024,1792): pack Wq|Wk|W6 -> wcat bf16 [1536][512]
__global__ __launch_bounds__(256) void prep(const float* __restrict__ x,
                                            const float* __restrict__ Wq,
                                            const float* __restrict__ Wk,
                                            const float* __restrict__ W6,
                                            short* __restrict__ xt,
                                            short* __restrict__ wcat) {
  const int bid = blockIdx.x, u = threadIdx.x;
  if (bid < 1024) {
    const int p0 = (bid & 15) * 64, c0 = ((bid >> 4) & 7) * 64, b = bid >> 7;
    __shared__ float t[64][65];
    {
      const int p4 = u & 15, cr = u >> 4;
      for (int cc = 0; cc < 4; ++cc) {
        const int c = cc * 16 + cr;
        const float4 v = *(const float4*)&x[((size_t)(b * 512 + c0 + c)) * 1024 + p0 + p4 * 4];
        t[p4 * 4 + 0][c] = v.x; t[p4 * 4 + 1][c] = v.y;
        t[p4 * 4 + 2][c] = v.z; t[p4 * 4 + 3][c] = v.w;
      }
    }
    __syncthreads();
    {
      const int c4 = u & 15, pr = u >> 4;
      for (int pp = 0; pp < 4; ++pp) {
        const int p = pp * 16 + pr;
        ushort4 o;
        o.x = f2bf(t[p][c4 * 4 + 0]); o.y = f2bf(t[p][c4 * 4 + 1]);
        o.z = f2bf(t[p][c4 * 4 + 2]); o.w = f2bf(t[p][c4 * 4 + 3]);
        *(ushort4*)&xt[((size_t)(b * 1024 + p0 + p)) * 512 + c0 + c4 * 4] = o;
      }
    }
  } else {
    const int i = (bid - 1024) * 256 + u;
    const int idx = i * 4;
    const float* src = (idx < 262144) ? Wq : (idx < 524288) ? Wk : W6;
    const float4 v = *(const float4*)&src[idx & 262143];
    ushort4 o;
    o.x = f2bf(v.x); o.y = f2bf(v.y); o.z = f2bf(v.z); o.w = f2bf(v.w);
    *(ushort4*)&wcat[idx] = o;
  }
}

// ---------------------------------------------------------------------------
// gemm_qkz: C[8192][1536] = xt @ wcat^T, R5-hybrid structure.
// Block 128x128, grid (64,12); wave w owns rows [m0+w*32,+32): acc[2][8].
// A streamed per-lane from global; B staged in LDS in 4 K-chunks, 32 KB LDS.
// Cols 0..1023 -> qk8 fp8 (+bias, HW v_cvt_pk_fp8_f32); 1024..1535 -> z bf16.
__global__ __launch_bounds__(256) void gemm_qkz(const short* __restrict__ xt,
                                                const short* __restrict__ wcat,
                                                const float* __restrict__ bq,
                                                const float* __restrict__ bk,
                                                unsigned char* __restrict__ qk8,
                                                short* __restrict__ z) {
  __shared__ short lds_b[16384];  // 32 KB: 8 j-groups x 4 kb x 512 shorts
  const int tid = threadIdx.x, w = tid >> 6, lane = tid & 63;
  const int quad = lane >> 4, lcol = lane & 15;
  const int srow = lane & 15, skq = lane >> 4;  // staging: row in j-group, 8-elem quad
  const int m0 = blockIdx.x * 128, n0 = blockIdx.y * 128;

  f32x4 acc[2][8];
#pragma unroll
  for (int rg = 0; rg < 2; ++rg)
#pragma unroll
    for (int j = 0; j < 8; ++j)
#pragma unroll
      for (int r = 0; r < 4; ++r) acc[rg][j][r] = 0.f;

  // A: per-lane; row = m0 + w*32 + rg*16 + srow, k-elems kh*128 + kb*32 + skq*8
  const short* Abase = xt + (size_t)(m0 + w * 32 + srow) * 512 + skq * 8;
  // B: staging source; row = n0 + j*16 + srow
  const short* Bbase = wcat + (size_t)(n0 + srow) * 512 + skq * 8;

#pragma unroll
  for (int kh = 0; kh < 4; ++kh) {
    const int ke = kh * 128;  // k-elem base of this chunk
    __syncthreads();  // previous chunk fully consumed before overwrite
#pragma unroll
    for (int jj = 0; jj < 2; ++jj) {
      const int j = w * 2 + jj;
#pragma unroll
      for (int kb = 0; kb < 4; ++kb)
        gload_lds16(Bbase + (size_t)(j * 16) * 512 + ke + kb * 32,
                    lds_b + j * 2048 + kb * 512);
    }
    // prefetch this chunk's A (2 rg x 4 kb x 16 B) while glds are in flight
    bf16x8 af[2][4];
#pragma unroll
    for (int rg = 0; rg < 2; ++rg)
#pragma unroll
      for (int kb = 0; kb < 4; ++kb)
        af[rg][kb] = *(const bf16x8*)(Abase + (size_t)rg * 16 * 512 + ke + kb * 32);
    __syncthreads();  // B chunk ready
#pragma unroll
    for (int kb = 0; kb < 4; ++kb) {
#pragma unroll
      for (int j = 0; j < 8; ++j) {
        const bf16x8 bf = *(const bf16x8*)&lds_b[j * 2048 + kb * 512 + lane * 8];
#pragma unroll
        for (int rg = 0; rg < 2; ++rg)
          acc[rg][j] = __builtin_amdgcn_mfma_f32_16x16x32_bf16(af[rg][kb], bf, acc[rg][j], 0, 0, 0);
      }
    }
  }

  const int region = (int)blockIdx.y >> 2;  // 0=q, 1=k, 2=z (uniform per block)
  if (region < 2) {
    const float* bias = region ? bk : bq;
#pragma unroll
    for (int rg = 0; rg < 2; ++rg) {
      const int row = m0 + w * 32 + rg * 16 + quad * 4;
#pragma unroll
      for (int j = 0; j < 8; ++j) {
        const int col = n0 + j * 16 + lcol;
        const float bv = bias[col & 511];
        const int p01 = __builtin_amdgcn_cvt_pk_fp8_f32(
            acc[rg][j][0] + bv, acc[rg][j][1] + bv, 0, false);
        const int p23 = __builtin_amdgcn_cvt_pk_fp8_f32(
            acc[rg][j][2] + bv, acc[rg][j][3] + bv, 0, false);
        qk8[(size_t)(row + 0) * 1024 + col] = (unsigned char)(p01 & 0xFF);
        qk8[(size_t)(row + 1) * 1024 + col] = (unsigned char)((p01 >> 8) & 0xFF);
        qk8[(size_t)(row + 2) * 1024 + col] = (unsigned char)(p23 & 0xFF);
        qk8[(size_t)(row + 3) * 1024 + col] = (unsigned char)((p23 >> 8) & 0xFF);
      }
    }
  } else {
#pragma unroll
    for (int rg = 0; rg < 2; ++rg) {
      const int row = m0 + w * 32 + rg * 16 + quad * 4;
#pragma unroll
      for (int j = 0; j < 8; ++j) {
        const int col = n0 - 1024 + j * 16 + lcol;
#pragma unroll
        for (int r = 0; r < 4; ++r)
          z[(size_t)(row + r) * 512 + col] = (short)f2bf(acc[rg][j][r]);
      }
    }
  }
}

// ---------------------------------------------------------------------------
// gemm_scores R8: q @ k^T via MX-fp8 mfma_scale_f32_32x32x64_f8f6f4, unit
// scales (lane maps hardware-verified R6/R7). grid (64 row-tiles, 8 images,
// 2 col-halves) = 1024 blocks x 4 waves = 4096 waves = 16/CU (breaks the
// 2048-wave cap of full-image waves). Block 256 thr: wave w owns rows
// [m0+w*32,+32) x the half-image's 512 cols; ns-loop over 8 x 64-col tiles.
// Per ns the verified single-buffer discipline:
//   sync ; stage 32 KB (wave stages j-group w>>1, kc-half w&1: 8 gload_lds) ;
//   sync ; compute 16 MFMA (8 kc x 2 j) ; fold vmax.
// LDS [2 j][8 kc][2 p][1 KB] = 32 KB -> 4 blocks/CU (128 KB). A rolling
// per-kc from global (ns-invariant -> L1-hot; R6 measured 88 VGPR for this
// per-wave structure). Partial per-row max -> wsmx[img*2+half][row]
// ([16][8192]); softmax_xw folds the pair (R7-verified). C/D row map:
// row_local = (r&3) + 8*(r>>2) + 4*(lane>>5).
__global__ __launch_bounds__(256) void gemm_scores(const unsigned char* __restrict__ qk8,
                                                   float* __restrict__ wsmx) {
  __shared__ unsigned char lds_b[32768];  // 2 j x 8 kc x 2 p x 1 KB
  const int tid = threadIdx.x, w = tid >> 6, lane = tid & 63;
  const int l31 = lane & 31, lh = lane >> 5;
  const int m0 = blockIdx.x * 128;
  const int img = blockIdx.y;        // image = 1024-col stripe
  const int half = blockIdx.z;       // col-half within image
  const int n0 = img * 1024 + half * 512;
  const int wrow = m0 + w * 32;      // this wave's 32 output rows

  // A source (q half): row = wrow + l31, k-bytes = kc*64 + lh*32 + [0,32)
  const unsigned char* Abase = qk8 + (size_t)(wrow + l31) * 1024 + lh * 32;
  // B staging: wave w stages j-group jg = w>>1, kc-half kh2 = w&1.
  // col-row = n0 + ns*64 + jg*32 + l31 ; k-bytes = kh2*256 + kc'*64 + lh*32 + p*16
  const int jg = w >> 1, kh2 = w & 1;
  const unsigned char* Bbase =
      qk8 + (size_t)(n0 + jg * 32 + l31) * 1024 + 512 + kh2 * 256 + lh * 32;
  unsigned char* ldsst = lds_b + jg * 16384 + kh2 * 8192;

  f32x16 acc[2];
  float vmax[16];
#pragma unroll
  for (int r = 0; r < 16; ++r) vmax[r] = -1e30f;

  for (int ns = 0; ns < 8; ++ns) {
    __syncthreads();  // previous ns fully consumed before overwrite
#pragma unroll
    for (int kcp = 0; kcp < 4; ++kcp)
#pragma unroll
      for (int p = 0; p < 2; ++p)
        gload_lds16(Bbase + ns * 65536 + kcp * 64 + p * 16,
                    ldsst + kcp * 2048 + p * 1024);
    __syncthreads();  // all 32 KB staged (single vmcnt-0 drain per ns)

#pragma unroll
    for (int j = 0; j < 2; ++j)
#pragma unroll
      for (int r = 0; r < 16; ++r) acc[j][r] = 0.f;

#pragma unroll
    for (int kc = 0; kc < 8; ++kc) {
      const i32x8 af = *(const i32x8*)(Abase + kc * 64);
#pragma unroll
      for (int j = 0; j < 2; ++j) {
        i32x8 bf;
        *(i64x2*)&bf = *(const i64x2*)&lds_b[j * 16384 + kc * 2048 + lane * 16];
        *((i64x2*)&bf + 1) =
            *(const i64x2*)&lds_b[j * 16384 + kc * 2048 + 1024 + lane * 16];
        acc[j] = __builtin_amdgcn_mfma_scale_f32_32x32x64_f8f6f4(
            af, bf, acc[j], 0, 0, 0, 0x7F7F7F7F, 0, 0x7F7F7F7F);
      }
    }

    // fold this tile's cols into the running per-row max (in-lane part)
#pragma unroll
    for (int j = 0; j < 2; ++j)
#pragma unroll
      for (int r = 0; r < 16; ++r) vmax[r] = fmaxf(vmax[r], acc[j][r]);
  }

  // cross-lane reduce over 32 cols (xor<32 stays within each lh half; lh
  // halves hold different rows) and write partial max: wsmx[img*2+half][row]
#pragma unroll
  for (int r = 0; r < 16; ++r) {
    float v = vmax[r];
#pragma unroll
    for (int off = 1; off < 32; off <<= 1) v = fmaxf(v, __shfl_xor(v, off));
    if (l31 == 0) {
      const int row_local = (r & 3) + 8 * (r >> 2) + 4 * lh;
      wsmx[(size_t)(img * 2 + half) * 8192 + wrow + row_local] = v;
    }
  }
}

// ---------------------------------------------------------------------------
// softmax_xw: logit[m] = scale * mean_img( per-image max ); softmax per image.
// wsmx is [16][8192]: per (image, col-half) partial maxes from gemm_scores.
__global__ __launch_bounds__(1024) void softmax_xw(const float* __restrict__ wsmx,
                                                   float* __restrict__ xw) {
  const int b = blockIdx.x, p = threadIdx.x;
  const int m = b * 1024 + p;
  float s = 0.f;
#pragma unroll
  for (int img = 0; img < 8; ++img)
    s += fmaxf(wsmx[(size_t)(img * 2 + 0) * 8192 + m],
               wsmx[(size_t)(img * 2 + 1) * 8192 + m]);
  const float logit = s * 0.005524271728019903f;  // (1/8) * (1/sqrt(512))
  __shared__ float red[16];
  float v = logit;
#pragma unroll
  for (int off = 32; off >= 1; off >>= 1) v = fmaxf(v, __shfl_xor(v, off));
  if ((p & 63) == 0) red[p >> 6] = v;
  __syncthreads();
  float bmax = red[0];
#pragma unroll
  for (int t = 1; t < 16; ++t) bmax = fmaxf(bmax, red[t]);
  const float e = expf(logit - bmax);
  float sv = e;
#pragma unroll
  for (int off = 32; off >= 1; off >>= 1) sv += __shfl_xor(sv, off);
  __syncthreads();
  if ((p & 63) == 0) red[p >> 6] = sv;
  __syncthreads();
  float bsum = 0.f;
#pragma unroll
  for (int t = 0; t < 16; ++t) bsum += red[t];
  xw[m] = e / bsum;
}

// ---------------------------------------------------------------------------
// epilogue_out: out[b][co][p] = z[b*1024+p][co] * xw[b*1024+p] + b6[co]
// z in bf16. grid (16 p-tiles, 8 c-tiles, 8 b), block 256.
__global__ __launch_bounds__(256) void epilogue_out(const short* __restrict__ z,
                                                    const float* __restrict__ xw,
                                                    const float* __restrict__ b6,
                                                    float* __restrict__ out) {
  const int p0 = blockIdx.x * 64, c0 = blockIdx.y * 64, b = blockIdx.z;
  __shared__ float t[64][65];  // t[co][p]
  const int u = threadIdx.x;
  {
    const int c4 = u & 15, pr = u >> 4;
    for (int pp = 0; pp < 4; ++pp) {
      const int p = pp * 16 + pr;
      const ushort4 v = *(const ushort4*)&z[((size_t)(b * 1024 + p0 + p)) * 512 + c0 + c4 * 4];
      t[c4 * 4 + 0][p] = bf2f(v.x);
      t[c4 * 4 + 1][p] = bf2f(v.y);
      t[c4 * 4 + 2][p] = bf2f(v.z);
      t[c4 * 4 + 3][p] = bf2f(v.w);
    }
  }
  __syncthreads();
  {
    const int p4 = u & 15, cr = u >> 4;
    const float4 wv = *(const float4*)&xw[b * 1024 + p0 + p4 * 4];
    for (int cc = 0; cc < 4; ++cc) {
      const int co = cc * 16 + cr;
      const float bias = b6[c0 + co];
      float4 o;
      o.x = t[co][p4 * 4 + 0] * wv.x + bias;
      o.y = t[co][p4 * 4 + 1] * wv.y + bias;
      o.z = t[co][p4 * 4 + 2] * wv.z + bias;
      o.w = t[co][p4 * 4 + 3] * wv.w + bias;
      *(float4*)&out[((size_t)(b * 512 + c0 + co)) * 1024 + p0 + p4 * 4] = o;
    }
  }
}

// ---------------------------------------------------------------------------
extern "C" void kernel_launch(void* const* d_in, const int* in_sizes, int n_in,
                              void* d_out, int out_size, void* d_ws, size_t ws_size,
                              hipStream_t stream) {
  const float* x  = (const float*)d_in[0];
  const float* Wq = (const float*)d_in[1];
  const float* bq = (const float*)d_in[2];
  const float* Wk = (const float*)d_in[3];
  const float* bk = (const float*)d_in[4];
  const float* W6 = (const float*)d_in[5];
  const float* b6 = (const float*)d_in[6];
  float* out = (float*)d_out;

  char* ws = (char*)d_ws;
  short* xt          = (short*)(ws + 0);               //  8 MB  bf16 [8192][512]
  short* wcat        = (short*)(ws + 8388608);         //  1.5MB bf16 [1536][512]
  unsigned char* qk8 = (unsigned char*)(ws + 10485760);//  8 MB  fp8  [8192][1024]
  short* z           = (short*)(ws + 18874368);        //  8 MB  bf16 [8192][512]
  float* wsmx        = (float*)(ws + 27262976);        // 512KB fp32 [16][8192]
  float* xw          = (float*)(ws + 29360128);        // 32 KB  fp32 [8192]

  prep<<<1792, 256, 0, stream>>>(x, Wq, Wk, W6, xt, wcat);
  gemm_qkz<<<dim3(64, 12), 256, 0, stream>>>(xt, wcat, bq, bk, qk8, z);
  gemm_scores<<<dim3(64, 8, 2), 256, 0, stream>>>(qk8, wsmx);
  softmax_xw<<<8, 1024, 0, stream>>>(wsmx, xw);
  epilogue_out<<<dim3(16, 8, 8), 256, 0, stream>>>(z, xw, b6, out);
}

// Round 9
// 207.959 us; speedup vs baseline: 1.1969x; 1.1057x over previous
//
#include <hip/hip_runtime.h>

// B=8, C=512, H=W=32, HW=1024, M=8192. scale = 1/sqrt(512).
// prep (x transpose->bf16, W pack->bf16)
// gemm_qkz (bf16 MFMA, R5-hybrid: A per-lane global, B staged LDS frag-ordered,
//           8 barriers; q|k -> fp8 qk8 via v_cvt_pk_fp8_f32 (+bias), z -> bf16)
// gemm_scores (R9 = R8 geometry + __launch_bounds__(256,4).
//              R8 root-cause: allocator hoisted the 8 ns-invariant A-frags
//              (64 VGPR) -> 164 VGPR -> 10.8% occupancy. Cap at 128 makes it
//              reload A per ns (L1-hot, rematerializable); un-hoisted live
//              set ~95 fits WITHOUT spilling (unlike R2 where live set >128).
//              grid (64,8,2) x 4 waves = 16 waves/CU; 32 KB LDS -> 4 blk/CU.)
// softmax_xw ; epilogue_out (out = z*xw + b6, LDS transpose)

typedef __attribute__((ext_vector_type(8))) short bf16x8;
typedef __attribute__((ext_vector_type(4))) float f32x4;
typedef __attribute__((ext_vector_type(16))) float f32x16;
typedef __attribute__((ext_vector_type(2))) long long i64x2;
typedef __attribute__((ext_vector_type(8))) int i32x8;

__device__ __forceinline__ unsigned short f2bf(float f) {
  unsigned u = __builtin_bit_cast(unsigned, f);
  u += 0x7FFFu + ((u >> 16) & 1u);
  return (unsigned short)(u >> 16);
}

__device__ __forceinline__ float bf2f(unsigned short b) {
  return __builtin_bit_cast(float, (unsigned)b << 16);
}

__device__ __forceinline__ void gload_lds16(const void* g, void* l) {
  __builtin_amdgcn_global_load_lds(
      (const __attribute__((address_space(1))) unsigned int*)g,
      (__attribute__((address_space(3))) unsigned int*)l, 16, 0, 0);
}

// ---------------------------------------------------------------------------
// prep: blocks [0,1024): transpose x [b][c][p] -> xt [b*1024+p][c] bf16
//       blocks [1024,1792): pack Wq|Wk|W6 -> wcat bf16 [1536][512]
__global__ __launch_bounds__(256) void prep(const float* __restrict__ x,
                                            const float* __restrict__ Wq,
                                            const float* __restrict__ Wk,
                                            const float* __restrict__ W6,
                                            short* __restrict__ xt,
                                            short* __restrict__ wcat) {
  const int bid = blockIdx.x, u = threadIdx.x;
  if (bid < 1024) {
    const int p0 = (bid & 15) * 64, c0 = ((bid >> 4) & 7) * 64, b = bid >> 7;
    __shared__ float t[64][65];
    {
      const int p4 = u & 15, cr = u >> 4;
      for (int cc = 0; cc < 4; ++cc) {
        const int c = cc * 16 + cr;
        const float4 v = *(const float4*)&x[((size_t)(b * 512 + c0 + c)) * 1024 + p0 + p4 * 4];
        t[p4 * 4 + 0][c] = v.x; t[p4 * 4 + 1][c] = v.y;
        t[p4 * 4 + 2][c] = v.z; t[p4 * 4 + 3][c] = v.w;
      }
    }
    __syncthreads();
    {
      const int c4 = u & 15, pr = u >> 4;
      for (int pp = 0; pp < 4; ++pp) {
        const int p = pp * 16 + pr;
        ushort4 o;
        o.x = f2bf(t[p][c4 * 4 + 0]); o.y = f2bf(t[p][c4 * 4 + 1]);
        o.z = f2bf(t[p][c4 * 4 + 2]); o.w = f2bf(t[p][c4 * 4 + 3]);
        *(ushort4*)&xt[((size_t)(b * 1024 + p0 + p)) * 512 + c0 + c4 * 4] = o;
      }
    }
  } else {
    const int i = (bid - 1024) * 256 + u;
    const int idx = i * 4;
    const float* src = (idx < 262144) ? Wq : (idx < 524288) ? Wk : W6;
    const float4 v = *(const float4*)&src[idx & 262143];
    ushort4 o;
    o.x = f2bf(v.x); o.y = f2bf(v.y); o.z = f2bf(v.z); o.w = f2bf(v.w);
    *(ushort4*)&wcat[idx] = o;
  }
}

// ---------------------------------------------------------------------------
// gemm_qkz: C[8192][1536] = xt @ wcat^T, R5-hybrid structure.
// Block 128x128, grid (64,12); wave w owns rows [m0+w*32,+32): acc[2][8].
// A streamed per-lane from global; B staged in LDS in 4 K-chunks, 32 KB LDS.
// Cols 0..1023 -> qk8 fp8 (+bias, HW v_cvt_pk_fp8_f32); 1024..1535 -> z bf16.
__global__ __launch_bounds__(256) void gemm_qkz(const short* __restrict__ xt,
                                                const short* __restrict__ wcat,
                                                const float* __restrict__ bq,
                                                const float* __restrict__ bk,
                                                unsigned char* __restrict__ qk8,
                                                short* __restrict__ z) {
  __shared__ short lds_b[16384];  // 32 KB: 8 j-groups x 4 kb x 512 shorts
  const int tid = threadIdx.x, w = tid >> 6, lane = tid & 63;
  const int quad = lane >> 4, lcol = lane & 15;
  const int srow = lane & 15, skq = lane >> 4;  // staging: row in j-group, 8-elem quad
  const int m0 = blockIdx.x * 128, n0 = blockIdx.y * 128;

  f32x4 acc[2][8];
#pragma unroll
  for (int rg = 0; rg < 2; ++rg)
#pragma unroll
    for (int j = 0; j < 8; ++j)
#pragma unroll
      for (int r = 0; r < 4; ++r) acc[rg][j][r] = 0.f;

  // A: per-lane; row = m0 + w*32 + rg*16 + srow, k-elems kh*128 + kb*32 + skq*8
  const short* Abase = xt + (size_t)(m0 + w * 32 + srow) * 512 + skq * 8;
  // B: staging source; row = n0 + j*16 + srow
  const short* Bbase = wcat + (size_t)(n0 + srow) * 512 + skq * 8;

#pragma unroll
  for (int kh = 0; kh < 4; ++kh) {
    const int ke = kh * 128;  // k-elem base of this chunk
    __syncthreads();  // previous chunk fully consumed before overwrite
#pragma unroll
    for (int jj = 0; jj < 2; ++jj) {
      const int j = w * 2 + jj;
#pragma unroll
      for (int kb = 0; kb < 4; ++kb)
        gload_lds16(Bbase + (size_t)(j * 16) * 512 + ke + kb * 32,
                    lds_b + j * 2048 + kb * 512);
    }
    // prefetch this chunk's A (2 rg x 4 kb x 16 B) while glds are in flight
    bf16x8 af[2][4];
#pragma unroll
    for (int rg = 0; rg < 2; ++rg)
#pragma unroll
      for (int kb = 0; kb < 4; ++kb)
        af[rg][kb] = *(const bf16x8*)(Abase + (size_t)rg * 16 * 512 + ke + kb * 32);
    __syncthreads();  // B chunk ready
#pragma unroll
    for (int kb = 0; kb < 4; ++kb) {
#pragma unroll
      for (int j = 0; j < 8; ++j) {
        const bf16x8 bf = *(const bf16x8*)&lds_b[j * 2048 + kb * 512 + lane * 8];
#pragma unroll
        for (int rg = 0; rg < 2; ++rg)
          acc[rg][j] = __builtin_amdgcn_mfma_f32_16x16x32_bf16(af[rg][kb], bf, acc[rg][j], 0, 0, 0);
      }
    }
  }

  const int region = (int)blockIdx.y >> 2;  // 0=q, 1=k, 2=z (uniform per block)
  if (region < 2) {
    const float* bias = region ? bk : bq;
#pragma unroll
    for (int rg = 0; rg < 2; ++rg) {
      const int row = m0 + w * 32 + rg * 16 + quad * 4;
#pragma unroll
      for (int j = 0; j < 8; ++j) {
        const int col = n0 + j * 16 + lcol;
        const float bv = bias[col & 511];
        const int p01 = __builtin_amdgcn_cvt_pk_fp8_f32(
            acc[rg][j][0] + bv, acc[rg][j][1] + bv, 0, false);
        const int p23 = __builtin_amdgcn_cvt_pk_fp8_f32(
            acc[rg][j][2] + bv, acc[rg][j][3] + bv, 0, false);
        qk8[(size_t)(row + 0) * 1024 + col] = (unsigned char)(p01 & 0xFF);
        qk8[(size_t)(row + 1) * 1024 + col] = (unsigned char)((p01 >> 8) & 0xFF);
        qk8[(size_t)(row + 2) * 1024 + col] = (unsigned char)(p23 & 0xFF);
        qk8[(size_t)(row + 3) * 1024 + col] = (unsigned char)((p23 >> 8) & 0xFF);
      }
    }
  } else {
#pragma unroll
    for (int rg = 0; rg < 2; ++rg) {
      const int row = m0 + w * 32 + rg * 16 + quad * 4;
#pragma unroll
      for (int j = 0; j < 8; ++j) {
        const int col = n0 - 1024 + j * 16 + lcol;
#pragma unroll
        for (int r = 0; r < 4; ++r)
          z[(size_t)(row + r) * 512 + col] = (short)f2bf(acc[rg][j][r]);
      }
    }
  }
}

// ---------------------------------------------------------------------------
// gemm_scores R9: q @ k^T via MX-fp8 mfma_scale_f32_32x32x64_f8f6f4, unit
// scales (lane maps hardware-verified R6/R7/R8). grid (64 row-tiles, 8
// images, 2 col-halves) = 1024 blocks x 4 waves = 16 waves/CU. Block 256:
// wave w owns rows [m0+w*32,+32) x the half-image's 512 cols; ns-loop over
// 8 x 64-col tiles. Per ns the verified single-buffer discipline:
//   sync ; stage 32 KB (wave stages j-group w>>1, kc-half w&1: 8 gload_lds) ;
//   sync ; compute 16 MFMA (8 kc x 2 j) ; fold vmax.
// __launch_bounds__(256,4) caps VGPR at 128: R8's allocator hoisted the 8
// ns-invariant A-frag loads (64 VGPR) -> 164 VGPR, 10.8% occupancy. The cap
// forces per-ns A reload (L1-hot remat, no spill: un-hoisted live set ~95,
// R6 measured 88 for this per-wave structure). LDS [2 j][8 kc][2 p][1 KB]
// = 32 KB -> 4 blocks/CU. Partial per-row max -> wsmx[img*2+half][row]
// ([16][8192]); softmax_xw folds the pair (R7/R8-verified). C/D row map:
// row_local = (r&3) + 8*(r>>2) + 4*(lane>>5).
__global__ __launch_bounds__(256, 4) void gemm_scores(const unsigned char* __restrict__ qk8,
                                                      float* __restrict__ wsmx) {
  __shared__ unsigned char lds_b[32768];  // 2 j x 8 kc x 2 p x 1 KB
  const int tid = threadIdx.x, w = tid >> 6, lane = tid & 63;
  const int l31 = lane & 31, lh = lane >> 5;
  const int m0 = blockIdx.x * 128;
  const int img = blockIdx.y;        // image = 1024-col stripe
  const int half = blockIdx.z;       // col-half within image
  const int n0 = img * 1024 + half * 512;
  const int wrow = m0 + w * 32;      // this wave's 32 output rows

  // A source (q half): row = wrow + l31, k-bytes = kc*64 + lh*32 + [0,32)
  const unsigned char* Abase = qk8 + (size_t)(wrow + l31) * 1024 + lh * 32;
  // B staging: wave w stages j-group jg = w>>1, kc-half kh2 = w&1.
  // col-row = n0 + ns*64 + jg*32 + l31 ; k-bytes = kh2*256 + kc'*64 + lh*32 + p*16
  const int jg = w >> 1, kh2 = w & 1;
  const unsigned char* Bbase =
      qk8 + (size_t)(n0 + jg * 32 + l31) * 1024 + 512 + kh2 * 256 + lh * 32;
  unsigned char* ldsst = lds_b + jg * 16384 + kh2 * 8192;

  f32x16 acc[2];
  float vmax[16];
#pragma unroll
  for (int r = 0; r < 16; ++r) vmax[r] = -1e30f;

  for (int ns = 0; ns < 8; ++ns) {
    __syncthreads();  // previous ns fully consumed before overwrite
#pragma unroll
    for (int kcp = 0; kcp < 4; ++kcp)
#pragma unroll
      for (int p = 0; p < 2; ++p)
        gload_lds16(Bbase + ns * 65536 + kcp * 64 + p * 16,
                    ldsst + kcp * 2048 + p * 1024);
    __syncthreads();  // all 32 KB staged (single vmcnt-0 drain per ns)

#pragma unroll
    for (int j = 0; j < 2; ++j)
#pragma unroll
      for (int r = 0; r < 16; ++r) acc[j][r] = 0.f;

#pragma unroll
    for (int kc = 0; kc < 8; ++kc) {
      const i32x8 af = *(const i32x8*)(Abase + kc * 64);
#pragma unroll
      for (int j = 0; j < 2; ++j) {
        i32x8 bf;
        *(i64x2*)&bf = *(const i64x2*)&lds_b[j * 16384 + kc * 2048 + lane * 16];
        *((i64x2*)&bf + 1) =
            *(const i64x2*)&lds_b[j * 16384 + kc * 2048 + 1024 + lane * 16];
        acc[j] = __builtin_amdgcn_mfma_scale_f32_32x32x64_f8f6f4(
            af, bf, acc[j], 0, 0, 0, 0x7F7F7F7F, 0, 0x7F7F7F7F);
      }
    }

    // fold this tile's cols into the running per-row max (in-lane part)
#pragma unroll
    for (int j = 0; j < 2; ++j)
#pragma unroll
      for (int r = 0; r < 16; ++r) vmax[r] = fmaxf(vmax[r], acc[j][r]);
  }

  // cross-lane reduce over 32 cols (xor<32 stays within each lh half; lh
  // halves hold different rows) and write partial max: wsmx[img*2+half][row]
#pragma unroll
  for (int r = 0; r < 16; ++r) {
    float v = vmax[r];
#pragma unroll
    for (int off = 1; off < 32; off <<= 1) v = fmaxf(v, __shfl_xor(v, off));
    if (l31 == 0) {
      const int row_local = (r & 3) + 8 * (r >> 2) + 4 * lh;
      wsmx[(size_t)(img * 2 + half) * 8192 + wrow + row_local] = v;
    }
  }
}

// ---------------------------------------------------------------------------
// softmax_xw: logit[m] = scale * mean_img( per-image max ); softmax per image.
// wsmx is [16][8192]: per (image, col-half) partial maxes from gemm_scores.
__global__ __launch_bounds__(1024) void softmax_xw(const float* __restrict__ wsmx,
                                                   float* __restrict__ xw) {
  const int b = blockIdx.x, p = threadIdx.x;
  const int m = b * 1024 + p;
  float s = 0.f;
#pragma unroll
  for (int img = 0; img < 8; ++img)
    s += fmaxf(wsmx[(size_t)(img * 2 + 0) * 8192 + m],
               wsmx[(size_t)(img * 2 + 1) * 8192 + m]);
  const float logit = s * 0.005524271728019903f;  // (1/8) * (1/sqrt(512))
  __shared__ float red[16];
  float v = logit;
#pragma unroll
  for (int off = 32; off >= 1; off >>= 1) v = fmaxf(v, __shfl_xor(v, off));
  if ((p & 63) == 0) red[p >> 6] = v;
  __syncthreads();
  float bmax = red[0];
#pragma unroll
  for (int t = 1; t < 16; ++t) bmax = fmaxf(bmax, red[t]);
  const float e = expf(logit - bmax);
  float sv = e;
#pragma unroll
  for (int off = 32; off >= 1; off >>= 1) sv += __shfl_xor(sv, off);
  __syncthreads();
  if ((p & 63) == 0) red[p >> 6] = sv;
  __syncthreads();
  float bsum = 0.f;
#pragma unroll
  for (int t = 0; t < 16; ++t) bsum += red[t];
  xw[m] = e / bsum;
}

// ---------------------------------------------------------------------------
// epilogue_out: out[b][co][p] = z[b*1024+p][co] * xw[b*1024+p] + b6[co]
// z in bf16. grid (16 p-tiles, 8 c-tiles, 8 b), block 256.
__global__ __launch_bounds__(256) void epilogue_out(const short* __restrict__ z,
                                                    const float* __restrict__ xw,
                                                    const float* __restrict__ b6,
                                                    float* __restrict__ out) {
  const int p0 = blockIdx.x * 64, c0 = blockIdx.y * 64, b = blockIdx.z;
  __shared__ float t[64][65];  // t[co][p]
  const int u = threadIdx.x;
  {
    const int c4 = u & 15, pr = u >> 4;
    for (int pp = 0; pp < 4; ++pp) {
      const int p = pp * 16 + pr;
      const ushort4 v = *(const ushort4*)&z[((size_t)(b * 1024 + p0 + p)) * 512 + c0 + c4 * 4];
      t[c4 * 4 + 0][p] = bf2f(v.x);
      t[c4 * 4 + 1][p] = bf2f(v.y);
      t[c4 * 4 + 2][p] = bf2f(v.z);
      t[c4 * 4 + 3][p] = bf2f(v.w);
    }
  }
  __syncthreads();
  {
    const int p4 = u & 15, cr = u >> 4;
    const float4 wv = *(const float4*)&xw[b * 1024 + p0 + p4 * 4];
    for (int cc = 0; cc < 4; ++cc) {
      const int co = cc * 16 + cr;
      const float bias = b6[c0 + co];
      float4 o;
      o.x = t[co][p4 * 4 + 0] * wv.x + bias;
      o.y = t[co][p4 * 4 + 1] * wv.y + bias;
      o.z = t[co][p4 * 4 + 2] * wv.z + bias;
      o.w = t[co][p4 * 4 + 3] * wv.w + bias;
      *(float4*)&out[((size_t)(b * 512 + c0 + co)) * 1024 + p0 + p4 * 4] = o;
    }
  }
}

// ---------------------------------------------------------------------------
extern "C" void kernel_launch(void* const* d_in, const int* in_sizes, int n_in,
                              void* d_out, int out_size, void* d_ws, size_t ws_size,
                              hipStream_t stream) {
  const float* x  = (const float*)d_in[0];
  const float* Wq = (const float*)d_in[1];
  const float* bq = (const float*)d_in[2];
  const float* Wk = (const float*)d_in[3];
  const float* bk = (const float*)d_in[4];
  const float* W6 = (const float*)d_in[5];
  const float* b6 = (const float*)d_in[6];
  float* out = (float*)d_out;

  char* ws = (char*)d_ws;
  short* xt          = (short*)(ws + 0);               //  8 MB  bf16 [8192][512]
  short* wcat        = (short*)(ws + 8388608);         //  1.5MB bf16 [1536][512]
  unsigned char* qk8 = (unsigned char*)(ws + 10485760);//  8 MB  fp8  [8192][1024]
  short* z           = (short*)(ws + 18874368);        //  8 MB  bf16 [8192][512]
  float* wsmx        = (float*)(ws + 27262976);        // 512KB fp32 [16][8192]
  float* xw          = (float*)(ws + 29360128);        // 32 KB  fp32 [8192]

  prep<<<1792, 256, 0, stream>>>(x, Wq, Wk, W6, xt, wcat);
  gemm_qkz<<<dim3(64, 12), 256, 0, stream>>>(xt, wcat, bq, bk, qk8, z);
  gemm_scores<<<dim3(64, 8, 2), 256, 0, stream>>>(qk8, wsmx);
  softmax_xw<<<8, 1024, 0, stream>>>(wsmx, xw);
  epilogue_out<<<dim3(16, 8, 8), 256, 0, stream>>>(z, xw, b6, out);
}

// Round 10
// 154.212 us; speedup vs baseline: 1.6141x; 1.3485x over previous
//
#include <hip/hip_runtime.h>

// B=8, C=512, H=W=32, HW=1024, M=8192. scale = 1/sqrt(512).
// prep (x transpose->bf16, W pack->bf16)
// gemm_qkz (bf16 MFMA, R5-hybrid: A per-lane global, B staged LDS frag-ordered,
//           8 barriers; q|k -> fp8 qk8 via v_cvt_pk_fp8_f32 (+bias), z -> bf16)
// gemm_scores (R5 EXACT, banked best: MX-fp8 16x16x128 unit scales, grid
//              (64,8), 8 waves, A resident af[4], batched 64KB staging,
//              verified single-buffer discipline, 45.7 us measured.
//              R6-R9 32x32 arc: all 4 decompositions lost to this -- wave
//              cap / spill / hoist / serialized A-loads. Closed.)
// epilogue_out (R10: FUSED softmax -- computes image softmax from wsmx
//              in-block (redundant, L2-hot, ~2us aggregate) then
//              out = z*xw + b6. Kills the softmax_xw launch: 5 -> 4 kernels.)

typedef __attribute__((ext_vector_type(8))) short bf16x8;
typedef __attribute__((ext_vector_type(4))) float f32x4;
typedef __attribute__((ext_vector_type(2))) long long i64x2;
typedef __attribute__((ext_vector_type(8))) int i32x8;

__device__ __forceinline__ unsigned short f2bf(float f) {
  unsigned u = __builtin_bit_cast(unsigned, f);
  u += 0x7FFFu + ((u >> 16) & 1u);
  return (unsigned short)(u >> 16);
}

__device__ __forceinline__ float bf2f(unsigned short b) {
  return __builtin_bit_cast(float, (unsigned)b << 16);
}

__device__ __forceinline__ void gload_lds16(const void* g, void* l) {
  __builtin_amdgcn_global_load_lds(
      (const __attribute__((address_space(1))) unsigned int*)g,
      (__attribute__((address_space(3))) unsigned int*)l, 16, 0, 0);
}

// ---------------------------------------------------------------------------
// prep: blocks [0,1024): transpose x [b][c][p] -> xt [b*1024+p][c] bf16
//       blocks [1024,1792): pack Wq|Wk|W6 -> wcat bf16 [1536][512]
__global__ __launch_bounds__(256) void prep(const float* __restrict__ x,
                                            const float* __restrict__ Wq,
                                            const float* __restrict__ Wk,
                                            const float* __restrict__ W6,
                                            short* __restrict__ xt,
                                            short* __restrict__ wcat) {
  const int bid = blockIdx.x, u = threadIdx.x;
  if (bid < 1024) {
    const int p0 = (bid & 15) * 64, c0 = ((bid >> 4) & 7) * 64, b = bid >> 7;
    __shared__ float t[64][65];
    {
      const int p4 = u & 15, cr = u >> 4;
      for (int cc = 0; cc < 4; ++cc) {
        const int c = cc * 16 + cr;
        const float4 v = *(const float4*)&x[((size_t)(b * 512 + c0 + c)) * 1024 + p0 + p4 * 4];
        t[p4 * 4 + 0][c] = v.x; t[p4 * 4 + 1][c] = v.y;
        t[p4 * 4 + 2][c] = v.z; t[p4 * 4 + 3][c] = v.w;
      }
    }
    __syncthreads();
    {
      const int c4 = u & 15, pr = u >> 4;
      for (int pp = 0; pp < 4; ++pp) {
        const int p = pp * 16 + pr;
        ushort4 o;
        o.x = f2bf(t[p][c4 * 4 + 0]); o.y = f2bf(t[p][c4 * 4 + 1]);
        o.z = f2bf(t[p][c4 * 4 + 2]); o.w = f2bf(t[p][c4 * 4 + 3]);
        *(ushort4*)&xt[((size_t)(b * 1024 + p0 + p)) * 512 + c0 + c4 * 4] = o;
      }
    }
  } else {
    const int i = (bid - 1024) * 256 + u;
    const int idx = i * 4;
    const float* src = (idx < 262144) ? Wq : (idx < 524288) ? Wk : W6;
    const float4 v = *(const float4*)&src[idx & 262143];
    ushort4 o;
    o.x = f2bf(v.x); o.y = f2bf(v.y); o.z = f2bf(v.z); o.w = f2bf(v.w);
    *(ushort4*)&wcat[idx] = o;
  }
}

// ---------------------------------------------------------------------------
// gemm_qkz: C[8192][1536] = xt @ wcat^T, R5-hybrid structure.
// Block 128x128, grid (64,12); wave w owns rows [m0+w*32,+32): acc[2][8].
// A streamed per-lane from global; B staged in LDS in 4 K-chunks, 32 KB LDS.
// Cols 0..1023 -> qk8 fp8 (+bias, HW v_cvt_pk_fp8_f32); 1024..1535 -> z bf16.
__global__ __launch_bounds__(256) void gemm_qkz(const short* __restrict__ xt,
                                                const short* __restrict__ wcat,
                                                const float* __restrict__ bq,
                                                const float* __restrict__ bk,
                                                unsigned char* __restrict__ qk8,
                                                short* __restrict__ z) {
  __shared__ short lds_b[16384];  // 32 KB: 8 j-groups x 4 kb x 512 shorts
  const int tid = threadIdx.x, w = tid >> 6, lane = tid & 63;
  const int quad = lane >> 4, lcol = lane & 15;
  const int srow = lane & 15, skq = lane >> 4;  // staging: row in j-group, 8-elem quad
  const int m0 = blockIdx.x * 128, n0 = blockIdx.y * 128;

  f32x4 acc[2][8];
#pragma unroll
  for (int rg = 0; rg < 2; ++rg)
#pragma unroll
    for (int j = 0; j < 8; ++j)
#pragma unroll
      for (int r = 0; r < 4; ++r) acc[rg][j][r] = 0.f;

  // A: per-lane; row = m0 + w*32 + rg*16 + srow, k-elems kh*128 + kb*32 + skq*8
  const short* Abase = xt + (size_t)(m0 + w * 32 + srow) * 512 + skq * 8;
  // B: staging source; row = n0 + j*16 + srow
  const short* Bbase = wcat + (size_t)(n0 + srow) * 512 + skq * 8;

#pragma unroll
  for (int kh = 0; kh < 4; ++kh) {
    const int ke = kh * 128;  // k-elem base of this chunk
    __syncthreads();  // previous chunk fully consumed before overwrite
#pragma unroll
    for (int jj = 0; jj < 2; ++jj) {
      const int j = w * 2 + jj;
#pragma unroll
      for (int kb = 0; kb < 4; ++kb)
        gload_lds16(Bbase + (size_t)(j * 16) * 512 + ke + kb * 32,
                    lds_b + j * 2048 + kb * 512);
    }
    // prefetch this chunk's A (2 rg x 4 kb x 16 B) while glds are in flight
    bf16x8 af[2][4];
#pragma unroll
    for (int rg = 0; rg < 2; ++rg)
#pragma unroll
      for (int kb = 0; kb < 4; ++kb)
        af[rg][kb] = *(const bf16x8*)(Abase + (size_t)rg * 16 * 512 + ke + kb * 32);
    __syncthreads();  // B chunk ready
#pragma unroll
    for (int kb = 0; kb < 4; ++kb) {
#pragma unroll
      for (int j = 0; j < 8; ++j) {
        const bf16x8 bf = *(const bf16x8*)&lds_b[j * 2048 + kb * 512 + lane * 8];
#pragma unroll
        for (int rg = 0; rg < 2; ++rg)
          acc[rg][j] = __builtin_amdgcn_mfma_f32_16x16x32_bf16(af[rg][kb], bf, acc[rg][j], 0, 0, 0);
      }
    }
  }

  const int region = (int)blockIdx.y >> 2;  // 0=q, 1=k, 2=z (uniform per block)
  if (region < 2) {
    const float* bias = region ? bk : bq;
#pragma unroll
    for (int rg = 0; rg < 2; ++rg) {
      const int row = m0 + w * 32 + rg * 16 + quad * 4;
#pragma unroll
      for (int j = 0; j < 8; ++j) {
        const int col = n0 + j * 16 + lcol;
        const float bv = bias[col & 511];
        const int p01 = __builtin_amdgcn_cvt_pk_fp8_f32(
            acc[rg][j][0] + bv, acc[rg][j][1] + bv, 0, false);
        const int p23 = __builtin_amdgcn_cvt_pk_fp8_f32(
            acc[rg][j][2] + bv, acc[rg][j][3] + bv, 0, false);
        qk8[(size_t)(row + 0) * 1024 + col] = (unsigned char)(p01 & 0xFF);
        qk8[(size_t)(row + 1) * 1024 + col] = (unsigned char)((p01 >> 8) & 0xFF);
        qk8[(size_t)(row + 2) * 1024 + col] = (unsigned char)(p23 & 0xFF);
        qk8[(size_t)(row + 3) * 1024 + col] = (unsigned char)((p23 >> 8) & 0xFF);
      }
    }
  } else {
#pragma unroll
    for (int rg = 0; rg < 2; ++rg) {
      const int row = m0 + w * 32 + rg * 16 + quad * 4;
#pragma unroll
      for (int j = 0; j < 8; ++j) {
        const int col = n0 - 1024 + j * 16 + lcol;
#pragma unroll
        for (int r = 0; r < 4; ++r)
          z[(size_t)(row + r) * 512 + col] = (short)f2bf(acc[rg][j][r]);
      }
    }
  }
}

// ---------------------------------------------------------------------------
// gemm_scores: R5 EXACT (45.7 us measured, banked). q @ k^T via MX-fp8
// mfma_scale_f32_16x16x128_f8f6f4, unit scales (E8M0 0x7F = 2^0).
// grid (64 row-tiles, 8 images), block 512 = 8 waves; wave w owns rows
// [m0+w*16,+16); block covers the image's 1024 cols in 8 n-subs (ns).
// A loaded ONCE into registers: af[4] = 4 x i32x8 (K=512, 128 B/lane).
// Per ns the verified single-buffer discipline:
//   sync ; stage 64 KB (8 gload_lds/wave, both K-halves batched -> ONE
//   drain per 32 MFMAs) ; sync ; compute ; fold max.
// LDS [8 j][2 kh][2 kc][2 p][1 KB]; frag read = two b128 at lane*16/+1024,
// conflict-free. Per-image row-max folded in-kernel -> wsmx[8][8192].
__global__ __launch_bounds__(512) void gemm_scores(const unsigned char* __restrict__ qk8,
                                                   float* __restrict__ wsmx) {
  __shared__ unsigned char lds_b[65536];  // 8 j x 2 kh x 2 kc x 2 p x 1 KB
  const int tid = threadIdx.x, w = tid >> 6, lane = tid & 63;
  const int quad = lane >> 4, lcol = lane & 15;
  const int srow = lane & 15, skb = (lane >> 4) * 32;  // staging row / k-offset
  const int m0 = blockIdx.x * 128;
  const int img = blockIdx.y;  // image = 1024-col stripe
  const int n0 = img * 1024;

  // A resident: row = m0 + w*16 + srow, k-bytes kk*128 + quad*32 + [0,32)
  const unsigned char* Abase = qk8 + (size_t)(m0 + w * 16 + srow) * 1024 + quad * 32;
  i32x8 af[4];
#pragma unroll
  for (int kk = 0; kk < 4; ++kk) af[kk] = *(const i32x8*)(Abase + kk * 128);

  // B staging source: row = n0 + ns*128 + w*16 + srow (wave stages j-group w),
  // k-bytes (k half of qk8 row): kh*256 + kc*128 + quad*32 + p*16
  const unsigned char* Bbase = qk8 + (size_t)(n0 + w * 16 + srow) * 1024 + 512 + skb;
  unsigned char* ldsw = lds_b + w * 8192;

  f32x4 acc[8];
  float vmax[4] = {-1e30f, -1e30f, -1e30f, -1e30f};

  for (int ns = 0; ns < 8; ++ns) {
    __syncthreads();  // previous ns fully consumed before overwrite
#pragma unroll
    for (int kh = 0; kh < 2; ++kh)
#pragma unroll
      for (int kc = 0; kc < 2; ++kc)
#pragma unroll
        for (int p = 0; p < 2; ++p)
          gload_lds16(Bbase + ns * 131072 + kh * 256 + kc * 128 + p * 16,
                      ldsw + kh * 4096 + kc * 2048 + p * 1024);
    __syncthreads();  // all 64 KB staged (single vmcnt-0 drain per ns)

#pragma unroll
    for (int j = 0; j < 8; ++j)
#pragma unroll
      for (int r = 0; r < 4; ++r) acc[j][r] = 0.f;

#pragma unroll
    for (int kh = 0; kh < 2; ++kh)
#pragma unroll
      for (int kc = 0; kc < 2; ++kc)
#pragma unroll
        for (int j = 0; j < 8; ++j) {
          i32x8 bf;
          *(i64x2*)&bf =
              *(const i64x2*)&lds_b[j * 8192 + kh * 4096 + kc * 2048 + lane * 16];
          *((i64x2*)&bf + 1) =
              *(const i64x2*)&lds_b[j * 8192 + kh * 4096 + kc * 2048 + 1024 + lane * 16];
          acc[j] = __builtin_amdgcn_mfma_scale_f32_16x16x128_f8f6f4(
              af[kh * 2 + kc], bf, acc[j], 0, 0, 0, 0x7F7F7F7F, 0, 0x7F7F7F7F);
        }

    // fold this n-sub's cols into the running per-row max (in-lane part)
#pragma unroll
    for (int j = 0; j < 8; ++j)
#pragma unroll
      for (int r = 0; r < 4; ++r) vmax[r] = fmaxf(vmax[r], acc[j][r]);
  }

  // cross-lane (16-lane col group) reduce + write per-image max: wsmx[img][row]
#pragma unroll
  for (int r = 0; r < 4; ++r) {
    float v = vmax[r];
#pragma unroll
    for (int off = 1; off < 16; off <<= 1) v = fmaxf(v, __shfl_xor(v, off));
    if (lcol == 0)
      wsmx[(size_t)img * 8192 + m0 + w * 16 + quad * 4 + r] = v;
  }
}

// ---------------------------------------------------------------------------
// epilogue_out R10: fused softmax + gating + transpose.
// Per block (p-tile, c-tile, b): (1) compute the FULL image-b softmax from
// wsmx[8][8192] (redundant across the image's 128 blocks; 64 KB of L2-hot
// float4 reads + block max/sum reduce -- ~2us aggregate, saves a launch);
// (2) out[b][co][p] = z[b*1024+p][co] * xw + b6[co] via LDS transpose.
// logit[m] = (1/8/sqrt(512)) * sum_img wsmx[img][m]; xw = softmax per image.
__global__ __launch_bounds__(256) void epilogue_out(const short* __restrict__ z,
                                                    const float* __restrict__ wsmx,
                                                    const float* __restrict__ b6,
                                                    float* __restrict__ out) {
  const int p0 = blockIdx.x * 64, c0 = blockIdx.y * 64, b = blockIdx.z;
  __shared__ float t[64][65];  // t[co][p]
  __shared__ float ev[1024];   // exp(logit - bmax) for all pixels of image b
  __shared__ float red[2][4];  // per-wave partial max / sum
  const int u = threadIdx.x;

  // ---- fused softmax: thread u owns pixels u*4..u*4+3 of image b ----
  float lg[4];
  {
    float4 s4 = make_float4(0.f, 0.f, 0.f, 0.f);
#pragma unroll
    for (int img = 0; img < 8; ++img) {
      const float4 v = *(const float4*)&wsmx[(size_t)img * 8192 + b * 1024 + u * 4];
      s4.x += v.x; s4.y += v.y; s4.z += v.z; s4.w += v.w;
    }
    const float sc = 0.005524271728019903f;  // (1/8) * (1/sqrt(512))
    lg[0] = s4.x * sc; lg[1] = s4.y * sc; lg[2] = s4.z * sc; lg[3] = s4.w * sc;
  }
  float lmax = fmaxf(fmaxf(lg[0], lg[1]), fmaxf(lg[2], lg[3]));
#pragma unroll
  for (int off = 32; off >= 1; off >>= 1) lmax = fmaxf(lmax, __shfl_xor(lmax, off));
  if ((u & 63) == 0) red[0][u >> 6] = lmax;
  __syncthreads();
  const float bmax = fmaxf(fmaxf(red[0][0], red[0][1]), fmaxf(red[0][2], red[0][3]));
  float lsum = 0.f;
#pragma unroll
  for (int i = 0; i < 4; ++i) {
    const float e = expf(lg[i] - bmax);
    ev[u * 4 + i] = e;
    lsum += e;
  }
#pragma unroll
  for (int off = 32; off >= 1; off >>= 1) lsum += __shfl_xor(lsum, off);
  if ((u & 63) == 0) red[1][u >> 6] = lsum;

  // ---- stage z tile into LDS (transpose) while softmax sum settles ----
  {
    const int c4 = u & 15, pr = u >> 4;
    for (int pp = 0; pp < 4; ++pp) {
      const int p = pp * 16 + pr;
      const ushort4 v = *(const ushort4*)&z[((size_t)(b * 1024 + p0 + p)) * 512 + c0 + c4 * 4];
      t[c4 * 4 + 0][p] = bf2f(v.x);
      t[c4 * 4 + 1][p] = bf2f(v.y);
      t[c4 * 4 + 2][p] = bf2f(v.z);
      t[c4 * 4 + 3][p] = bf2f(v.w);
    }
  }
  __syncthreads();  // t[][] ready AND red[1]/ev[] ready
  const float inv_bsum = 1.f / (red[1][0] + red[1][1] + red[1][2] + red[1][3]);
  {
    const int p4 = u & 15, cr = u >> 4;
    const float4 wv = make_float4(ev[p0 + p4 * 4 + 0] * inv_bsum,
                                  ev[p0 + p4 * 4 + 1] * inv_bsum,
                                  ev[p0 + p4 * 4 + 2] * inv_bsum,
                                  ev[p0 + p4 * 4 + 3] * inv_bsum);
    for (int cc = 0; cc < 4; ++cc) {
      const int co = cc * 16 + cr;
      const float bias = b6[c0 + co];
      float4 o;
      o.x = t[co][p4 * 4 + 0] * wv.x + bias;
      o.y = t[co][p4 * 4 + 1] * wv.y + bias;
      o.z = t[co][p4 * 4 + 2] * wv.z + bias;
      o.w = t[co][p4 * 4 + 3] * wv.w + bias;
      *(float4*)&out[((size_t)(b * 512 + c0 + co)) * 1024 + p0 + p4 * 4] = o;
    }
  }
}

// ---------------------------------------------------------------------------
extern "C" void kernel_launch(void* const* d_in, const int* in_sizes, int n_in,
                              void* d_out, int out_size, void* d_ws, size_t ws_size,
                              hipStream_t stream) {
  const float* x  = (const float*)d_in[0];
  const float* Wq = (const float*)d_in[1];
  const float* bq = (const float*)d_in[2];
  const float* Wk = (const float*)d_in[3];
  const float* bk = (const float*)d_in[4];
  const float* W6 = (const float*)d_in[5];
  const float* b6 = (const float*)d_in[6];
  float* out = (float*)d_out;

  char* ws = (char*)d_ws;
  short* xt          = (short*)(ws + 0);               //  8 MB  bf16 [8192][512]
  short* wcat        = (short*)(ws + 8388608);         //  1.5MB bf16 [1536][512]
  unsigned char* qk8 = (unsigned char*)(ws + 10485760);//  8 MB  fp8  [8192][1024]
  short* z           = (short*)(ws + 18874368);        //  8 MB  bf16 [8192][512]
  float* wsmx        = (float*)(ws + 27262976);        // 256KB fp32 [8][8192]

  prep<<<1792, 256, 0, stream>>>(x, Wq, Wk, W6, xt, wcat);
  gemm_qkz<<<dim3(64, 12), 256, 0, stream>>>(xt, wcat, bq, bk, qk8, z);
  gemm_scores<<<dim3(64, 8), 512, 0, stream>>>(qk8, wsmx);
  epilogue_out<<<dim3(16, 8, 8), 256, 0, stream>>>(z, wsmx, b6, out);
}